// Round 8
// baseline (280.121 us; speedup 1.0000x reference)
//
#include <hip/hip_runtime.h>
#include <hip/hip_bf16.h>
#include <math.h>

typedef __attribute__((ext_vector_type(8))) __bf16 bf16x8;
typedef __attribute__((ext_vector_type(4))) float f32x4;
typedef __attribute__((ext_vector_type(4))) unsigned short u16x4;

#define TOKENS 32768
#define CDIM   768     // model dim
#define SLOTCAP 33536  // 262*128: 32768 tokens + <=6*127 pad, rounded to 128
#define MT_TILES 262   // SLOTCAP / 128
#define RBLOCKS 1024   // router grid; 4 waves/block, 8 tokens/wave

// async global->LDS, 16B per lane; LDS dest wave-uniform base + lane*16,
// global SOURCE address is per-lane (gather-capable).
__device__ __forceinline__ void async_copy16(const void* g, void* l) {
    __builtin_amdgcn_global_load_lds(
        (const __attribute__((address_space(1))) void*)g,
        (__attribute__((address_space(3))) void*)l, 16, 0, 0);
}

// exact-GELU via A&S 7.1.26 erf approx, |erf err| < 1.5e-7 (below bf16 eps)
__device__ __forceinline__ float fast_gelu(float v) {
    float x  = v * 0.70710678118654752f;
    float ax = fabsf(x);
    float t  = __builtin_amdgcn_rcpf(1.0f + 0.3275911f * ax);
    float poly = t * (0.254829592f +
                 t * (-0.284496736f +
                 t * (1.421413741f +
                 t * (-1.453152027f +
                 t * 1.061405429f))));
    float erfv = 1.0f - poly * __expf(-x * x);
    erfv = copysignf(erfv, x);
    return 0.5f * v * (1.0f + erfv);
}

// pair tables: p -> (lo,hi): 0:(0,1) 1:(0,2) 2:(0,3) 3:(1,2) 4:(1,3) 5:(2,3)
__device__ __forceinline__ int pair_lo(int p) { return p < 3 ? 0 : (p < 5 ? 1 : 2); }
__device__ __forceinline__ int pair_hi(int p) { return p < 3 ? p + 1 : (p < 5 ? p - 1 : 3); }

// padded (to 128) exclusive prefix of pair counts -> offs[0..5]
__device__ __forceinline__ void bucket_offs(const int* __restrict__ meta, int* offs) {
    int run = 0;
#pragma unroll
    for (int p = 0; p < 6; ++p) {
        offs[p] = run;
        run += ((meta[p] + 127) >> 7) << 7;
    }
}

// ---------------- weight prep + bucket-state init ----------------------------
__global__ __launch_bounds__(256) void prep_weights(
    const float* __restrict__ fc1w, const float* __restrict__ fc2w,
    __hip_bfloat16* __restrict__ b1, __hip_bfloat16* __restrict__ b2t,
    int* __restrict__ slots, float2* __restrict__ swt, int* __restrict__ meta)
{
    int idx = blockIdx.x * 256 + threadIdx.x;   // grid 2304*256 = 589824 exact
    if (idx < 32) meta[idx] = 0;
    if (idx < SLOTCAP) { slots[idx] = -1; swt[idx] = make_float2(0.f, 0.f); }
    // b1[n][k] = fc1_w[e][h][c] with n=e*192+h, k=c  -> flat identity
    b1[idx] = __float2bfloat16(fc1w[idx]);
    // b2t[c][e*192+h] = fc2_w[e][c][h]
    int c = idx / 768;
    int r = idx - c * 768;
    int e = r / 192;
    int h = r - e * 192;
    b2t[idx] = __float2bfloat16(fc2w[((size_t)e * 768 + c) * 192 + h]);
}

// ---------------- router + x fp32->bf16 conversion ---------------------------
// One wave per token, 8 tokens per wave; coalesced 1 KiB loads / 512 B stores;
// router weights hoisted; pair counts block-aggregated (<=6 atomics/block).
__global__ __launch_bounds__(256) void router_convert(
    const float* __restrict__ x, const float* __restrict__ rw,
    const float* __restrict__ rb,
    __hip_bfloat16* __restrict__ xb,
    int* __restrict__ pairid, float2* __restrict__ wpair, int* __restrict__ meta)
{
    __shared__ int rc[6];
    if (threadIdx.x < 6) rc[threadIdx.x] = 0;
    __syncthreads();

    const int wave = threadIdx.x >> 6;
    const int lane = threadIdx.x & 63;
    const int wid  = blockIdx.x * 4 + wave;      // 0..4095
    const int el   = lane * 4;                   // element within 256-chunk

    float4 wv[4][3];
#pragma unroll
    for (int e = 0; e < 4; ++e)
#pragma unroll
        for (int t = 0; t < 3; ++t)
            wv[e][t] = *(const float4*)(rw + e * CDIM + t * 256 + el);
    float rbv[4];
#pragma unroll
    for (int e = 0; e < 4; ++e) rbv[e] = rb[e];

    for (int it = 0; it < 8; ++it) {
        const int token = wid * 8 + it;
        const float* xr = x + (size_t)token * CDIM;

        float4 v[3];
#pragma unroll
        for (int t = 0; t < 3; ++t) v[t] = *(const float4*)(xr + t * 256 + el);

        unsigned short* xrow = (unsigned short*)xb + (size_t)token * CDIM;
#pragma unroll
        for (int t = 0; t < 3; ++t) {
            alignas(8) __hip_bfloat16 hb[4];
            hb[0] = __float2bfloat16(v[t].x);
            hb[1] = __float2bfloat16(v[t].y);
            hb[2] = __float2bfloat16(v[t].z);
            hb[3] = __float2bfloat16(v[t].w);
            *(u16x4*)(xrow + t * 256 + el) = *(const u16x4*)hb;
        }

        float s[4];
#pragma unroll
        for (int e = 0; e < 4; ++e) {
            s[e] = v[0].x * wv[e][0].x + v[0].y * wv[e][0].y
                 + v[0].z * wv[e][0].z + v[0].w * wv[e][0].w
                 + v[1].x * wv[e][1].x + v[1].y * wv[e][1].y
                 + v[1].z * wv[e][1].z + v[1].w * wv[e][1].w
                 + v[2].x * wv[e][2].x + v[2].y * wv[e][2].y
                 + v[2].z * wv[e][2].z + v[2].w * wv[e][2].w;
        }
#pragma unroll
        for (int e = 0; e < 4; ++e) {
            float vv = s[e];
            vv += __shfl_xor(vv, 32); vv += __shfl_xor(vv, 16); vv += __shfl_xor(vv, 8);
            vv += __shfl_xor(vv, 4);  vv += __shfl_xor(vv, 2);  vv += __shfl_xor(vv, 1);
            s[e] = vv;
        }
        float lg[4], p[4];
#pragma unroll
        for (int e = 0; e < 4; ++e) lg[e] = s[e] + rbv[e];
        float mx = fmaxf(fmaxf(lg[0], lg[1]), fmaxf(lg[2], lg[3]));
        float ps = 0.f;
#pragma unroll
        for (int e = 0; e < 4; ++e) { p[e] = __expf(lg[e] - mx); ps += p[e]; }
#pragma unroll
        for (int e = 0; e < 4; ++e) p[e] /= ps;
        int a = 0;
#pragma unroll
        for (int e = 1; e < 4; ++e) if (p[e] > p[a]) a = e;   // ties -> first (jax)
        int b = (a == 0) ? 1 : 0;
#pragma unroll
        for (int e = 0; e < 4; ++e) if (e != a && p[e] > p[b]) b = e;
        float wsum = p[a] + p[b] + 1e-8f;
        if (lane == 0) {
            int lo = a < b ? a : b;
            int hi = a < b ? b : a;
            int pid = (lo == 0) ? hi - 1 : (lo == 1 ? hi + 1 : 5);
            pairid[token] = pid;
            wpair[token] = make_float2(p[lo] / wsum, p[hi] / wsum);
            atomicAdd(&rc[pid], 1);   // LDS atomic
        }
    }
    __syncthreads();
    if (threadIdx.x < 6 && rc[threadIdx.x])
        atomicAdd(&meta[threadIdx.x], rc[threadIdx.x]);
}

// ---------------- scatter token ids into bucketed slots ----------------------
__global__ __launch_bounds__(256) void scatter_tokens(
    const int* __restrict__ pairid, const float2* __restrict__ wpair,
    int* __restrict__ slots, float2* __restrict__ swt, int* __restrict__ meta)
{
    __shared__ int sc[6], sb[6], soff[6];
    int tid = threadIdx.x;
    if (tid < 6) sc[tid] = 0;
    __syncthreads();
    int t = blockIdx.x * 256 + tid;         // grid = 128 -> t < 32768 always
    int p = pairid[t];
    int r = atomicAdd(&sc[p], 1);
    __syncthreads();
    if (tid == 0) {
        int offs[6];
        bucket_offs(meta, offs);
#pragma unroll
        for (int q = 0; q < 6; ++q) soff[q] = offs[q];
    }
    if (tid < 6) sb[tid] = sc[tid] ? atomicAdd(&meta[16 + tid], sc[tid]) : 0;
    __syncthreads();
    int pos = soff[p] + sb[p] + r;
    slots[pos] = t;
    swt[pos] = wpair[t];
}

// ---------------- GEMMs: BK=128, single-buffer 64 KB -------------------------
// Drain-count hypothesis: per-K-step cost is dominated by a fixed vmcnt(0)+
// barrier+latency stack (~4-6k cyc, traffic-independent). BK 64->128 halves
// the number of drains at identical staged bytes/MFMA count. LDS = A 32K +
// B 32K single buffer (2 blocks/CU -- r7 showed occupancy delta is ~free).
// Staging chunk = 4 rows x 16 granules (1 KiB); XOR swizzle on low-3 granule
// bits only (stays within the 64 B line -> coalescing preserved; ds_read
// conflict pattern unchanged).
#define BM 128
#define BN 128
#define BK 128

template <int MODE, int K, int NT>
__global__ __launch_bounds__(256) void gemm_moe(
    const __hip_bfloat16* __restrict__ A, const __hip_bfloat16* __restrict__ Bt,
    const int* __restrict__ slots, const float2* __restrict__ swt,
    const int* __restrict__ meta,
    const float* __restrict__ bias1,   // fc1_b flat [768] (MODE 0)
    const float* __restrict__ bias2,   // fc2_b [4][768]   (MODE 1)
    __hip_bfloat16* __restrict__ HW,   // MODE 0 output [SLOTCAP][384]
    float* __restrict__ OUT)           // MODE 1 output [32768][768]
{
    __shared__ __hip_bfloat16 smem[BM * BK + BN * BK];   // 64 KB single buffer

    const int tid = threadIdx.x;
    const int wave = tid >> 6, lane = tid & 63;
    const int wm = (wave >> 1) * 64, wn = (wave & 1) * 64;
    const int lrow = lane & 15, quad = lane >> 4;

    // bijective XCD-aware swizzle (m204 form)
    constexpr int nwg = MT_TILES * NT;
    constexpr int q = nwg >> 3, rr = nwg & 7;
    const int bid = blockIdx.x;
    const int xcd = bid & 7, sidx = bid >> 3;
    const int wg = (xcd < rr ? xcd * (q + 1) : rr * (q + 1) + (xcd - rr) * q) + sidx;
    const int by = wg / NT;
    const int bx = wg - by * NT;
    const int rowB0 = bx * BN;
    const int rowA0 = by * BM;

    // bucket (expert pair) of this M-tile; tiles never straddle buckets
    int offs[6];
    bucket_offs(meta, offs);
    int pb = 0;
#pragma unroll
    for (int i = 1; i < 6; ++i) pb += (rowA0 >= offs[i]) ? 1 : 0;
    const int lo = pair_lo(pb), hi = pair_hi(pb);

    // staging geometry: chunk = 4 rows x 16 granules of 8 elems (1 KiB).
    // 32 chunks per tile; wave stages chunks wave*8 + p (p<8) for A and B.
    // LDS linear position pg = lane&15; source granule sg = pg ^ (row&7)
    // (XOR low-3 bits only -> each lane-quad stays in one 64 B line).
    const int sr4 = lane >> 4;                  // 0..3 row within chunk
    const int pg  = lane & 15;                  // LDS granule position

    unsigned aoff[8], boff[8];
    __hip_bfloat16* ldsA[8];
#pragma unroll
    for (int p = 0; p < 8; ++p) {
        int c = wave * 8 + p;                   // chunk 0..31
        int rt = c * 4 + sr4;                   // tile row 0..127
        int sg = pg ^ (rt & 7);                 // source granule 0..15
        int sg8 = sg * 8;                       // element offset within K-chunk
        if (MODE == 0) {
            int tok = slots[rowA0 + rt];        // -1 pads -> clamp to 0
            tok = tok < 0 ? 0 : tok;
            aoff[p] = (unsigned)tok * 768u + sg8;
            int grow = rowB0 + rt;              // 0..383
            int gb = (grow < 192) ? lo * 192 + grow : hi * 192 + (grow - 192);
            boff[p] = (unsigned)gb * 768u + sg8;
        } else {
            aoff[p] = (unsigned)(rowA0 + rt) * 384u + sg8;
            // fc2 B: absolute k = k0 + sg8; expert-select per granule
            // (granule = 8 elems, 192 = 24*8 -> never straddles). Store the
            // row base + sg8; the per-k0 expert offset is added in stage().
            boff[p] = (unsigned)(rowB0 + rt) * 768u + sg8;
        }
        ldsA[p] = smem + c * 512;               // 4 rows * 128 elems per chunk
    }

    auto stage = [&](int k0) {
#pragma unroll
        for (int p = 0; p < 8; ++p) {
            async_copy16(A + aoff[p] + k0, ldsA[p]);
            unsigned badd;
            if (MODE == 0) {
                badd = (unsigned)k0;
            } else {
                int c = wave * 8 + p;
                int rt = c * 4 + sr4;
                int sg8 = (pg ^ (rt & 7)) * 8;
                int kabs = k0 + sg8;            // 0..383, granule-aligned
                badd = (unsigned)(k0 + (kabs < 192 ? lo * 192 : hi * 192 - 192));
            }
            async_copy16(Bt + boff[p] + badd, ldsA[p] + BM * BK);
        }
    };

    f32x4 acc[4][4] = {};
    constexpr int NIT = K / BK;     // 6 (fc1) / 3 (fc2)

#pragma unroll
    for (int it = 0; it < NIT; ++it) {
        stage(it * BK);
        __syncthreads();      // drains vmcnt(0): staged tile visible
        const __hip_bfloat16* As = smem;
        const __hip_bfloat16* Bs = smem + BM * BK;
#pragma unroll
        for (int kk = 0; kk < BK; kk += 32) {
            bf16x8 af[4], bfr[4];
#pragma unroll
            for (int i = 0; i < 4; ++i) {
                int row = wm + i * 16 + lrow;
                int gp = ((kk >> 3) + quad) ^ (lrow & 7);
                af[i] = *(const bf16x8*)(&As[row * BK + gp * 8]);
            }
#pragma unroll
            for (int j = 0; j < 4; ++j) {
                int row = wn + j * 16 + lrow;
                int gp = ((kk >> 3) + quad) ^ (lrow & 7);
                bfr[j] = *(const bf16x8*)(&Bs[row * BK + gp * 8]);
            }
#pragma unroll
            for (int i = 0; i < 4; ++i)
#pragma unroll
                for (int j = 0; j < 4; ++j)
                    acc[i][j] = __builtin_amdgcn_mfma_f32_16x16x32_bf16(
                        af[i], bfr[j], acc[i][j], 0, 0, 0);
        }
        __syncthreads();      // all waves done reading before next stage
    }

    // epilogue; C/D layout: col = lane&15, row = quad*4 + reg  [m89/m91]
    if (MODE == 0) {
        const bool hf = (rowB0 + wn) >= 192;   // wave-uniform half select
        float b1v[4];
#pragma unroll
        for (int j = 0; j < 4; ++j) {
            int col = rowB0 + wn + j * 16 + lrow;            // 0..383
            int ng = (col < 192) ? lo * 192 + col : hi * 192 + (col - 192);
            b1v[j] = bias1[ng];
        }
#pragma unroll
        for (int i = 0; i < 4; ++i) {
#pragma unroll
            for (int r = 0; r < 4; ++r) {
                int rowl = wm + i * 16 + quad * 4 + r;
                float2 wv = swt[rowA0 + rowl];               // (wlo,whi); 0 on pads
                float cwt = hf ? wv.y : wv.x;
                __hip_bfloat16* srow_p = &smem[rowl * BN + wn + lrow];
#pragma unroll
                for (int j = 0; j < 4; ++j) {
                    float v = fast_gelu(acc[i][j][r] + b1v[j]) * cwt;
                    srow_p[j * 16] = __float2bfloat16(v);
                }
            }
        }
        __syncthreads();
        // 128 rows x 256 B; 2048 uint4 chunks over 256 threads = 8 each
#pragma unroll
        for (int t = 0; t < 8; ++t) {
            int idx = t * 256 + tid;
            int row = idx >> 4;            // 0..127
            int c16 = (idx & 15) * 8;      // element col, 16B granules
            *(uint4*)(HW + (size_t)(rowA0 + row) * 384 + rowB0 + c16) =
                *(const uint4*)(&smem[row * BN + c16]);
        }
    } else {
        // bias via live-expert pair; fp32 tile = 64 KB fits smem exactly
        float blo[4], bhi[4];
#pragma unroll
        for (int j = 0; j < 4; ++j) {
            int col = rowB0 + wn + j * 16 + lrow;
            blo[j] = bias2[lo * 768 + col];
            bhi[j] = bias2[hi * 768 + col];
        }
        float* smf = (float*)smem;
#pragma unroll
        for (int i = 0; i < 4; ++i) {
#pragma unroll
            for (int r = 0; r < 4; ++r) {
                int rowl = wm + i * 16 + quad * 4 + r;
                float2 wv = swt[rowA0 + rowl];
                float* sr = smf + rowl * BN + wn + lrow;
#pragma unroll
                for (int j = 0; j < 4; ++j)
                    sr[j * 16] = acc[i][j][r] + wv.x * blo[j] + wv.y * bhi[j];
            }
        }
        __syncthreads();
        // coalesced writer: 128 rows x 512 B bursts; pad rows skipped
#pragma unroll
        for (int t = 0; t < 16; ++t) {
            int idx = t * 256 + tid;
            int row = idx >> 5;            // 0..127
            int ch  = idx & 31;            // float4 chunk within row
            int tok = slots[rowA0 + row];
            if (tok >= 0)
                *(float4*)(OUT + (size_t)tok * CDIM + rowB0 + ch * 4) =
                    *(const float4*)(smf + row * BN + ch * 4);
        }
    }
}

extern "C" void kernel_launch(void* const* d_in, const int* in_sizes, int n_in,
                              void* d_out, int out_size, void* d_ws, size_t ws_size,
                              hipStream_t stream)
{
    const float* x    = (const float*)d_in[0];
    const float* rw   = (const float*)d_in[1];
    const float* rb   = (const float*)d_in[2];
    const float* fc1w = (const float*)d_in[3];
    const float* fc1b = (const float*)d_in[4];
    const float* fc2w = (const float*)d_in[5];
    const float* fc2b = (const float*)d_in[6];
    float* out = (float*)d_out;

    // workspace layout (bytes), all 16B-aligned; total ~79.3 MB
    char* ws = (char*)d_ws;
    __hip_bfloat16* xb   = (__hip_bfloat16*)(ws);                // 32768*768*2 = 50331648
    __hip_bfloat16* hw   = (__hip_bfloat16*)(ws + 50331648);     // 33536*384*2 = 25755648
    __hip_bfloat16* b1   = (__hip_bfloat16*)(ws + 76087296);     // 1179648
    __hip_bfloat16* b2t  = (__hip_bfloat16*)(ws + 77266944);     // 1179648
    float2*         wpr  = (float2*)       (ws + 78446592);      // 262144
    float2*         swt  = (float2*)       (ws + 78708736);      // 268288
    int*            pid  = (int*)          (ws + 78977024);      // 131072
    int*            slots= (int*)          (ws + 79108096);      // 134144
    int*            meta = (int*)          (ws + 79242240);      // 128

    prep_weights<<<2304, 256, 0, stream>>>(fc1w, fc2w, b1, b2t, slots, swt, meta);
    router_convert<<<RBLOCKS, 256, 0, stream>>>(x, rw, rb, xb, pid, wpr, meta);
    scatter_tokens<<<TOKENS / 256, 256, 0, stream>>>(pid, wpr, slots, swt, meta);

    // fc1: M=33536 slots (gathered), N=384 (pair), K=768 -> 786 blocks, 6 drains
    gemm_moe<0, 768, 3><<<MT_TILES * 3, 256, 0, stream>>>(
        xb, b1, slots, swt, meta, fc1b, nullptr, hw, nullptr);
    // fc2: M=33536 slots, N=768, K=384 (pair) -> 1572 blocks, 3 drains
    gemm_moe<1, 384, 6><<<MT_TILES * 6, 256, 0, stream>>>(
        hw, b2t, slots, swt, meta, nullptr, fc2b, nullptr, out);
}

// Round 9
// 275.114 us; speedup vs baseline: 1.0182x; 1.0182x over previous
//
#include <hip/hip_runtime.h>
#include <hip/hip_bf16.h>
#include <math.h>

typedef __attribute__((ext_vector_type(8))) __bf16 bf16x8;
typedef __attribute__((ext_vector_type(4))) float f32x4;
typedef __attribute__((ext_vector_type(4))) unsigned short u16x4;

#define TOKENS 32768
#define CDIM   768     // model dim
#define SLOTCAP 33536  // 262*128: 32768 tokens + <=6*127 pad, rounded to 128
#define MT_TILES 262   // SLOTCAP / 128
#define RBLOCKS 1024   // router grid; 4 waves/block, 8 tokens/wave

// async global->LDS, 16B per lane; LDS dest wave-uniform base + lane*16,
// global SOURCE address is per-lane (gather-capable).
__device__ __forceinline__ void async_copy16(const void* g, void* l) {
    __builtin_amdgcn_global_load_lds(
        (const __attribute__((address_space(1))) void*)g,
        (__attribute__((address_space(3))) void*)l, 16, 0, 0);
}

// exact-GELU via A&S 7.1.26 erf approx, |erf err| < 1.5e-7 (below bf16 eps)
__device__ __forceinline__ float fast_gelu(float v) {
    float x  = v * 0.70710678118654752f;
    float ax = fabsf(x);
    float t  = __builtin_amdgcn_rcpf(1.0f + 0.3275911f * ax);
    float poly = t * (0.254829592f +
                 t * (-0.284496736f +
                 t * (1.421413741f +
                 t * (-1.453152027f +
                 t * 1.061405429f))));
    float erfv = 1.0f - poly * __expf(-x * x);
    erfv = copysignf(erfv, x);
    return 0.5f * v * (1.0f + erfv);
}

// pair tables: p -> (lo,hi): 0:(0,1) 1:(0,2) 2:(0,3) 3:(1,2) 4:(1,3) 5:(2,3)
__device__ __forceinline__ int pair_lo(int p) { return p < 3 ? 0 : (p < 5 ? 1 : 2); }
__device__ __forceinline__ int pair_hi(int p) { return p < 3 ? p + 1 : (p < 5 ? p - 1 : 3); }

// padded (to 128) exclusive prefix of pair counts -> offs[0..5]
__device__ __forceinline__ void bucket_offs(const int* __restrict__ meta, int* offs) {
    int run = 0;
#pragma unroll
    for (int p = 0; p < 6; ++p) {
        offs[p] = run;
        run += ((meta[p] + 127) >> 7) << 7;
    }
}

// ---------------- weight prep + bucket-state init ----------------------------
__global__ __launch_bounds__(256) void prep_weights(
    const float* __restrict__ fc1w, const float* __restrict__ fc2w,
    __hip_bfloat16* __restrict__ b1, __hip_bfloat16* __restrict__ b2t,
    int* __restrict__ slots, float2* __restrict__ swt, int* __restrict__ meta)
{
    int idx = blockIdx.x * 256 + threadIdx.x;   // grid 2304*256 = 589824 exact
    if (idx < 32) meta[idx] = 0;
    if (idx < SLOTCAP) { slots[idx] = -1; swt[idx] = make_float2(0.f, 0.f); }
    // b1[n][k] = fc1_w[e][h][c] with n=e*192+h, k=c  -> flat identity
    b1[idx] = __float2bfloat16(fc1w[idx]);
    // b2t[c][e*192+h] = fc2_w[e][c][h]
    int c = idx / 768;
    int r = idx - c * 768;
    int e = r / 192;
    int h = r - e * 192;
    b2t[idx] = __float2bfloat16(fc2w[((size_t)e * 768 + c) * 192 + h]);
}

// ---------------- router + x fp32->bf16 conversion ---------------------------
// One wave per token, 8 tokens per wave; coalesced 1 KiB loads / 512 B stores;
// router weights hoisted; pair counts block-aggregated (<=6 atomics/block).
__global__ __launch_bounds__(256) void router_convert(
    const float* __restrict__ x, const float* __restrict__ rw,
    const float* __restrict__ rb,
    __hip_bfloat16* __restrict__ xb,
    int* __restrict__ pairid, float2* __restrict__ wpair, int* __restrict__ meta)
{
    __shared__ int rc[6];
    if (threadIdx.x < 6) rc[threadIdx.x] = 0;
    __syncthreads();

    const int wave = threadIdx.x >> 6;
    const int lane = threadIdx.x & 63;
    const int wid  = blockIdx.x * 4 + wave;      // 0..4095
    const int el   = lane * 4;                   // element within 256-chunk

    float4 wv[4][3];
#pragma unroll
    for (int e = 0; e < 4; ++e)
#pragma unroll
        for (int t = 0; t < 3; ++t)
            wv[e][t] = *(const float4*)(rw + e * CDIM + t * 256 + el);
    float rbv[4];
#pragma unroll
    for (int e = 0; e < 4; ++e) rbv[e] = rb[e];

    for (int it = 0; it < 8; ++it) {
        const int token = wid * 8 + it;
        const float* xr = x + (size_t)token * CDIM;

        float4 v[3];
#pragma unroll
        for (int t = 0; t < 3; ++t) v[t] = *(const float4*)(xr + t * 256 + el);

        unsigned short* xrow = (unsigned short*)xb + (size_t)token * CDIM;
#pragma unroll
        for (int t = 0; t < 3; ++t) {
            alignas(8) __hip_bfloat16 hb[4];
            hb[0] = __float2bfloat16(v[t].x);
            hb[1] = __float2bfloat16(v[t].y);
            hb[2] = __float2bfloat16(v[t].z);
            hb[3] = __float2bfloat16(v[t].w);
            *(u16x4*)(xrow + t * 256 + el) = *(const u16x4*)hb;
        }

        float s[4];
#pragma unroll
        for (int e = 0; e < 4; ++e) {
            s[e] = v[0].x * wv[e][0].x + v[0].y * wv[e][0].y
                 + v[0].z * wv[e][0].z + v[0].w * wv[e][0].w
                 + v[1].x * wv[e][1].x + v[1].y * wv[e][1].y
                 + v[1].z * wv[e][1].z + v[1].w * wv[e][1].w
                 + v[2].x * wv[e][2].x + v[2].y * wv[e][2].y
                 + v[2].z * wv[e][2].z + v[2].w * wv[e][2].w;
        }
#pragma unroll
        for (int e = 0; e < 4; ++e) {
            float vv = s[e];
            vv += __shfl_xor(vv, 32); vv += __shfl_xor(vv, 16); vv += __shfl_xor(vv, 8);
            vv += __shfl_xor(vv, 4);  vv += __shfl_xor(vv, 2);  vv += __shfl_xor(vv, 1);
            s[e] = vv;
        }
        float lg[4], p[4];
#pragma unroll
        for (int e = 0; e < 4; ++e) lg[e] = s[e] + rbv[e];
        float mx = fmaxf(fmaxf(lg[0], lg[1]), fmaxf(lg[2], lg[3]));
        float ps = 0.f;
#pragma unroll
        for (int e = 0; e < 4; ++e) { p[e] = __expf(lg[e] - mx); ps += p[e]; }
#pragma unroll
        for (int e = 0; e < 4; ++e) p[e] /= ps;
        int a = 0;
#pragma unroll
        for (int e = 1; e < 4; ++e) if (p[e] > p[a]) a = e;   // ties -> first (jax)
        int b = (a == 0) ? 1 : 0;
#pragma unroll
        for (int e = 0; e < 4; ++e) if (e != a && p[e] > p[b]) b = e;
        float wsum = p[a] + p[b] + 1e-8f;
        if (lane == 0) {
            int lo = a < b ? a : b;
            int hi = a < b ? b : a;
            int pid = (lo == 0) ? hi - 1 : (lo == 1 ? hi + 1 : 5);
            pairid[token] = pid;
            wpair[token] = make_float2(p[lo] / wsum, p[hi] / wsum);
            atomicAdd(&rc[pid], 1);   // LDS atomic
        }
    }
    __syncthreads();
    if (threadIdx.x < 6 && rc[threadIdx.x])
        atomicAdd(&meta[threadIdx.x], rc[threadIdx.x]);
}

// ---------------- scatter token ids into bucketed slots ----------------------
__global__ __launch_bounds__(256) void scatter_tokens(
    const int* __restrict__ pairid, const float2* __restrict__ wpair,
    int* __restrict__ slots, float2* __restrict__ swt, int* __restrict__ meta)
{
    __shared__ int sc[6], sb[6], soff[6];
    int tid = threadIdx.x;
    if (tid < 6) sc[tid] = 0;
    __syncthreads();
    int t = blockIdx.x * 256 + tid;         // grid = 128 -> t < 32768 always
    int p = pairid[t];
    int r = atomicAdd(&sc[p], 1);
    __syncthreads();
    if (tid == 0) {
        int offs[6];
        bucket_offs(meta, offs);
#pragma unroll
        for (int q = 0; q < 6; ++q) soff[q] = offs[q];
    }
    if (tid < 6) sb[tid] = sc[tid] ? atomicAdd(&meta[16 + tid], sc[tid]) : 0;
    __syncthreads();
    int pos = soff[p] + sb[p] + r;
    slots[pos] = t;
    swt[pos] = wpair[t];
}

// ---------------- fc1: single-buffer 32 KB (round-7 measured-best) -----------
// 5 blocks/CU capacity -> all 786 blocks co-resident in one round (no tail);
// cross-block wave overlap hides the stage latency (m114 mechanism).
#define BM 128
#define BN 128
#define BK 64

__global__ __launch_bounds__(256) void fc1_moe(
    const __hip_bfloat16* __restrict__ A,    // xb [TOKENS][768]
    const __hip_bfloat16* __restrict__ Bt,   // b1 [768][768] (n-major)
    const int* __restrict__ slots, const float2* __restrict__ swt,
    const int* __restrict__ meta, const float* __restrict__ bias1,
    __hip_bfloat16* __restrict__ HW)         // [SLOTCAP][384]
{
    __shared__ __hip_bfloat16 smem[BM * BK * 2];   // single buffer, 32 KB

    const int tid = threadIdx.x;
    const int wave = tid >> 6, lane = tid & 63;
    const int wm = (wave >> 1) * 64, wn = (wave & 1) * 64;
    const int lrow = lane & 15, quad = lane >> 4;

    constexpr int NT = 3;
    constexpr int nwg = MT_TILES * NT;      // 786
    constexpr int q = nwg >> 3, rr = nwg & 7;
    const int bid = blockIdx.x;
    const int xcd = bid & 7, sidx = bid >> 3;
    const int wg = (xcd < rr ? xcd * (q + 1) : rr * (q + 1) + (xcd - rr) * q) + sidx;
    const int by = wg / NT;
    const int bx = wg - by * NT;
    const int rowB0 = bx * BN;              // 0..256
    const int rowA0 = by * BM;

    int offs[6];
    bucket_offs(meta, offs);
    int pb = 0;
#pragma unroll
    for (int i = 1; i < 6; ++i) pb += (rowA0 >= offs[i]) ? 1 : 0;
    const int lo = pair_lo(pb), hi = pair_hi(pb);

    const int srow = lane >> 3;                 // 0..7 row within 8-row chunk
    const int scol = ((lane & 7) ^ srow) * 8;   // XOR'd source granule (elems)

    size_t aoff[4], boff[4];
    __hip_bfloat16* ldsA[4];
#pragma unroll
    for (int p = 0; p < 4; ++p) {
        int c = wave * 4 + p;
        int arow = c * 8 + srow;                // 0..127 row within tile
        int tok = slots[rowA0 + arow];          // -1 pads -> clamp to 0
        tok = tok < 0 ? 0 : tok;
        aoff[p] = (size_t)tok * 768 + scol;     // gathered A row
        int grow = rowB0 + arow;                // 0..383
        int gb = (grow < 192) ? lo * 192 + grow : hi * 192 + (grow - 192);
        boff[p] = (size_t)gb * 768 + scol;
        ldsA[p] = smem + c * 8 * BK;
    }

    auto stage = [&](int k0) {
#pragma unroll
        for (int p = 0; p < 4; ++p) {
            async_copy16(A + aoff[p] + k0, ldsA[p]);
            async_copy16(Bt + boff[p] + k0, ldsA[p] + BM * BK);
        }
    };

    f32x4 acc[4][4] = {};
    constexpr int NIT = 768 / BK;     // 12

#pragma unroll
    for (int it = 0; it < NIT; ++it) {
        stage(it * BK);
        __syncthreads();      // drains vmcnt(0): staged tile visible
        const __hip_bfloat16* As = smem;
        const __hip_bfloat16* Bs = smem + BM * BK;
#pragma unroll
        for (int kk = 0; kk < BK; kk += 32) {
            bf16x8 af[4], bfr[4];
#pragma unroll
            for (int i = 0; i < 4; ++i) {
                int row = wm + i * 16 + lrow;
                int gp = ((kk >> 3) + quad) ^ (lrow & 7);
                af[i] = *(const bf16x8*)(&As[row * BK + gp * 8]);
            }
#pragma unroll
            for (int j = 0; j < 4; ++j) {
                int row = wn + j * 16 + lrow;
                int gp = ((kk >> 3) + quad) ^ (lrow & 7);
                bfr[j] = *(const bf16x8*)(&Bs[row * BK + gp * 8]);
            }
#pragma unroll
            for (int i = 0; i < 4; ++i)
#pragma unroll
                for (int j = 0; j < 4; ++j)
                    acc[i][j] = __builtin_amdgcn_mfma_f32_16x16x32_bf16(
                        af[i], bfr[j], acc[i][j], 0, 0, 0);
        }
        __syncthreads();      // all waves done reading before next stage
    }

    // epilogue; C/D layout: col = lane&15, row = quad*4 + reg  [m89/m91]
    const bool hf = (rowB0 + wn) >= 192;   // wave-uniform half select
    float b1v[4];
#pragma unroll
    for (int j = 0; j < 4; ++j) {
        int col = rowB0 + wn + j * 16 + lrow;            // 0..383
        int ng = (col < 192) ? lo * 192 + col : hi * 192 + (col - 192);
        b1v[j] = bias1[ng];
    }
#pragma unroll
    for (int i = 0; i < 4; ++i) {
#pragma unroll
        for (int r = 0; r < 4; ++r) {
            int rowl = wm + i * 16 + quad * 4 + r;
            float2 wv = swt[rowA0 + rowl];               // (wlo,whi); 0 on pads
            float cwt = hf ? wv.y : wv.x;
            __hip_bfloat16* srow_p = &smem[rowl * BN + wn + lrow];
#pragma unroll
            for (int j = 0; j < 4; ++j) {
                float v = fast_gelu(acc[i][j][r] + b1v[j]) * cwt;
                srow_p[j * 16] = __float2bfloat16(v);
            }
        }
    }
    __syncthreads();
    // 128 rows x 256 B; 2048 uint4 chunks over 256 threads = 8 each
#pragma unroll
    for (int t = 0; t < 8; ++t) {
        int idx = t * 256 + tid;
        int row = idx >> 4;            // 0..127
        int c16 = (idx & 15) * 8;      // element col, 16B granules
        *(uint4*)(HW + (size_t)(rowA0 + row) * 384 + rowB0 + c16) =
            *(const uint4*)(&smem[row * BN + c16]);
    }
}

// ---------------- fc2: double-buffered 64 KB (round-4 measured-best) ---------
// Short K (6 steps) needs the 1-deep prefetch; one-pass 64 KB fp32 epilogue.
__global__ __launch_bounds__(256) void fc2_moe(
    const __hip_bfloat16* __restrict__ A,    // hw [SLOTCAP][384]
    const __hip_bfloat16* __restrict__ Bt,   // b2t [768][768] (c-major)
    const int* __restrict__ slots, const float2* __restrict__ swt,
    const int* __restrict__ meta, const float* __restrict__ bias2,
    float* __restrict__ OUT)                 // [32768][768]
{
    __shared__ __hip_bfloat16 smem[BM * BK * 4];   // 2 dbuf x (A,B) = 64 KB

    const int tid = threadIdx.x;
    const int wave = tid >> 6, lane = tid & 63;
    const int wm = (wave >> 1) * 64, wn = (wave & 1) * 64;
    const int lrow = lane & 15, quad = lane >> 4;

    constexpr int NT = 6;
    constexpr int nwg = MT_TILES * NT;      // 1572
    constexpr int q = nwg >> 3, rr = nwg & 7;
    const int bid = blockIdx.x;
    const int xcd = bid & 7, sidx = bid >> 3;
    const int wg = (xcd < rr ? xcd * (q + 1) : rr * (q + 1) + (xcd - rr) * q) + sidx;
    const int by = wg / NT;
    const int bx = wg - by * NT;
    const int rowB0 = bx * BN;
    const int rowA0 = by * BM;

    int offs[6];
    bucket_offs(meta, offs);
    int pb = 0;
#pragma unroll
    for (int i = 1; i < 6; ++i) pb += (rowA0 >= offs[i]) ? 1 : 0;
    const int lo = pair_lo(pb), hi = pair_hi(pb);

    const int srow = lane >> 3;
    const int scol = ((lane & 7) ^ srow) * 8;

    size_t aoff[4], boff[4];
    __hip_bfloat16* ldsA[4];
#pragma unroll
    for (int p = 0; p < 4; ++p) {
        int c = wave * 4 + p;
        int arow = c * 8 + srow;
        aoff[p] = (size_t)(rowA0 + arow) * 384 + scol;
        boff[p] = (size_t)(rowB0 + arow) * 768 + scol;
        ldsA[p] = smem + c * 8 * BK;
    }

    auto stage = [&](int buf, int k0) {
        int bo = buf * (2 * BM * BK);
        // source col = k + (k<192 ? lo*192 : hi*192-192); 64-wide chunks never
        // straddle 192, so the half is k0-uniform and swizzle-compatible.
        size_t badd = (size_t)(k0 < 192 ? lo * 192 : hi * 192 - 192) + k0;
#pragma unroll
        for (int p = 0; p < 4; ++p) {
            async_copy16(A + aoff[p] + k0, ldsA[p] + bo);
            async_copy16(Bt + boff[p] + badd, ldsA[p] + bo + BM * BK);
        }
    };

    f32x4 acc[4][4] = {};
    constexpr int NIT = 384 / BK;     // 6

    stage(0, 0);
    __syncthreads();
#pragma unroll
    for (int it = 0; it < NIT; ++it) {
        if (it + 1 < NIT) stage((it + 1) & 1, (it + 1) * BK);
        const __hip_bfloat16* As = smem + (it & 1) * (2 * BM * BK);
        const __hip_bfloat16* Bs = As + BM * BK;
#pragma unroll
        for (int kk = 0; kk < BK; kk += 32) {
            bf16x8 af[4], bfr[4];
#pragma unroll
            for (int i = 0; i < 4; ++i) {
                int row = wm + i * 16 + lrow;
                int gp = ((kk >> 3) + quad) ^ (lrow & 7);
                af[i] = *(const bf16x8*)(&As[row * BK + gp * 8]);
            }
#pragma unroll
            for (int j = 0; j < 4; ++j) {
                int row = wn + j * 16 + lrow;
                int gp = ((kk >> 3) + quad) ^ (lrow & 7);
                bfr[j] = *(const bf16x8*)(&Bs[row * BK + gp * 8]);
            }
#pragma unroll
            for (int i = 0; i < 4; ++i)
#pragma unroll
                for (int j = 0; j < 4; ++j)
                    acc[i][j] = __builtin_amdgcn_mfma_f32_16x16x32_bf16(
                        af[i], bfr[j], acc[i][j], 0, 0, 0);
        }
        __syncthreads();
    }

    // epilogue: bias via live-expert pair, LDS-staged coalesced float4 writer
    float blo[4], bhi[4];
#pragma unroll
    for (int j = 0; j < 4; ++j) {
        int col = rowB0 + wn + j * 16 + lrow;
        blo[j] = bias2[lo * 768 + col];
        bhi[j] = bias2[hi * 768 + col];
    }
    float* smf = (float*)smem;
#pragma unroll
    for (int i = 0; i < 4; ++i) {
#pragma unroll
        for (int r = 0; r < 4; ++r) {
            int rowl = wm + i * 16 + quad * 4 + r;
            float2 wv = swt[rowA0 + rowl];
            float* sr = smf + rowl * BN + wn + lrow;
#pragma unroll
            for (int j = 0; j < 4; ++j)
                sr[j * 16] = acc[i][j][r] + wv.x * blo[j] + wv.y * bhi[j];
        }
    }
    __syncthreads();
#pragma unroll
    for (int t = 0; t < 16; ++t) {
        int idx = t * 256 + tid;
        int row = idx >> 5;
        int ch  = idx & 31;
        int tok = slots[rowA0 + row];
        if (tok >= 0)
            *(float4*)(OUT + (size_t)tok * CDIM + rowB0 + ch * 4) =
                *(const float4*)(smf + row * BN + ch * 4);
    }
}

extern "C" void kernel_launch(void* const* d_in, const int* in_sizes, int n_in,
                              void* d_out, int out_size, void* d_ws, size_t ws_size,
                              hipStream_t stream)
{
    const float* x    = (const float*)d_in[0];
    const float* rw   = (const float*)d_in[1];
    const float* rb   = (const float*)d_in[2];
    const float* fc1w = (const float*)d_in[3];
    const float* fc1b = (const float*)d_in[4];
    const float* fc2w = (const float*)d_in[5];
    const float* fc2b = (const float*)d_in[6];
    float* out = (float*)d_out;

    // workspace layout (bytes), all 16B-aligned; total ~79.3 MB
    char* ws = (char*)d_ws;
    __hip_bfloat16* xb   = (__hip_bfloat16*)(ws);                // 32768*768*2 = 50331648
    __hip_bfloat16* hw   = (__hip_bfloat16*)(ws + 50331648);     // 33536*384*2 = 25755648
    __hip_bfloat16* b1   = (__hip_bfloat16*)(ws + 76087296);     // 1179648
    __hip_bfloat16* b2t  = (__hip_bfloat16*)(ws + 77266944);     // 1179648
    float2*         wpr  = (float2*)       (ws + 78446592);      // 262144
    float2*         swt  = (float2*)       (ws + 78708736);      // 268288
    int*            pid  = (int*)          (ws + 78977024);      // 131072
    int*            slots= (int*)          (ws + 79108096);      // 134144
    int*            meta = (int*)          (ws + 79242240);      // 128

    prep_weights<<<2304, 256, 0, stream>>>(fc1w, fc2w, b1, b2t, slots, swt, meta);
    router_convert<<<RBLOCKS, 256, 0, stream>>>(x, rw, rb, xb, pid, wpr, meta);
    scatter_tokens<<<TOKENS / 256, 256, 0, stream>>>(pid, wpr, slots, swt, meta);

    // fc1: single-buffer 32 KB, 786 blocks all co-resident (r7 best half)
    fc1_moe<<<MT_TILES * 3, 256, 0, stream>>>(
        xb, b1, slots, swt, meta, fc1b, hw);
    // fc2: double-buffered 64 KB, 1572 blocks (r4 best half)
    fc2_moe<<<MT_TILES * 6, 256, 0, stream>>>(
        hw, b2t, slots, swt, meta, fc2b, out);
}